// Round 1
// baseline (294.662 us; speedup 1.0000x reference)
//
#include <hip/hip_runtime.h>

// Problem constants
#define NS        4607          // series length: 512 + 4095
#define NBLK1     2048          // kernel-1 blocks (partial sums)
#define N_TOTAL   16777216.0    // 4096*512*8 elements in recon sum

__device__ __forceinline__ float wave_sum(float v) {
    for (int o = 32; o > 0; o >>= 1) v += __shfl_down(v, o);
    return v;
}

// -------- Kernel 1: recon partial sums  q = sum(log_var + (x-m)^2 * exp(-log_var)) --------
__global__ __launch_bounds__(256) void recon_kernel(
    const float* __restrict__ x, const float* __restrict__ dec,
    float* __restrict__ partials)
{
    const int tid = threadIdx.x;
    float acc = 0.f;
    const long long pix0 = (long long)blockIdx.x * 1024 + tid;
#pragma unroll
    for (int j = 0; j < 4; ++j) {
        const long long pix = pix0 + (long long)j * 256;
        const float4* xp = (const float4*)(x + pix * 8);
        const float4* dp = (const float4*)(dec + pix * 16);
        float4 x0 = xp[0], x1 = xp[1];
        float4 m0 = dp[0], m1 = dp[1];
        float4 l0 = dp[2], l1 = dp[3];
        float d;
        d = x0.x - m0.x; acc += l0.x + d * d * __expf(-l0.x);
        d = x0.y - m0.y; acc += l0.y + d * d * __expf(-l0.y);
        d = x0.z - m0.z; acc += l0.z + d * d * __expf(-l0.z);
        d = x0.w - m0.w; acc += l0.w + d * d * __expf(-l0.w);
        d = x1.x - m1.x; acc += l1.x + d * d * __expf(-l1.x);
        d = x1.y - m1.y; acc += l1.y + d * d * __expf(-l1.y);
        d = x1.z - m1.z; acc += l1.z + d * d * __expf(-l1.z);
        d = x1.w - m1.w; acc += l1.w + d * d * __expf(-l1.w);
    }
    acc = wave_sum(acc);
    __shared__ float s4[4];
    if ((tid & 63) == 0) s4[tid >> 6] = acc;
    __syncthreads();
    if (tid == 0) partials[blockIdx.x] = s4[0] + s4[1] + s4[2] + s4[3];
}

// -------- Kernel 2: series gather + ACL + GARCH + final combine --------
__global__ __launch_bounds__(256) void tail_kernel(
    const float* __restrict__ dec, const float* __restrict__ partials,
    float* __restrict__ out)
{
    const float OMEGA = 0.05f, ALPHA = 0.1f, BETA = 0.85f;
    const int tid  = threadIdx.x;
    const int lane = tid & 63;
    const int wv   = tid >> 6;

    __shared__ float  sc[NS];
    __shared__ float  s4[4];
    __shared__ double d4[4];
    __shared__ float  chunk_e[256], chunk_p[256], chunk_in[256];
    __shared__ float  aclw[4];
    __shared__ float  g_shared;

    // 1) gather series s into LDS, local sum for mean
    float lsum = 0.f;
    for (int j = tid; j < NS; j += 256) {
        float v = (j < 512) ? dec[(long long)j * 16]
                            : dec[(long long)(j - 511) * 8192 + 8176];
        sc[j] = v;
        lsum += v;
    }
    lsum = wave_sum(lsum);
    __syncthreads();
    if (lane == 0) s4[wv] = lsum;
    __syncthreads();
    const float mean = (s4[0] + s4[1] + s4[2] + s4[3]) / (float)NS;

    // 2) center in place, accumulate variance
    float vsum = 0.f;
    __syncthreads();
    for (int j = tid; j < NS; j += 256) {
        float v = sc[j] - mean;
        sc[j] = v;
        vsum += v * v;
    }
    vsum = wave_sum(vsum);
    __syncthreads();
    if (lane == 0) s4[wv] = vsum;
    __syncthreads();
    const float var = s4[0] + s4[1] + s4[2] + s4[3];

    // 3) ACL: lags 1..50, one lag-subset per wave, lanes stride the series
    float aclpart = 0.f;
    for (int k = wv + 1; k <= 50; k += 4) {
        float a = 0.f;
        for (int i = lane; i < NS - k; i += 64)
            a += sc[i] * sc[i + k];
        a = wave_sum(a);
        if (lane == 0) { float r = a / var; aclpart += r * r; }
    }
    if (lane == 0) aclw[wv] = aclpart;

    // 4) GARCH: chunked parallel linear-recurrence scan (L=18 per thread)
    const int start = tid * 18;
    const int end   = min(start + 18, NS);
    float e = 0.f, p = 1.f;
    for (int i = start; i < end; ++i) {
        float r2 = sc[i] * sc[i];
        e = (OMEGA + ALPHA * r2) + BETA * e;
        p *= BETA;
    }
    chunk_e[tid] = e; chunk_p[tid] = p;
    __syncthreads();
    if (tid == 0) {
        float carry = 1.0f;  // sigma0 = OMEGA/(1-ALPHA-BETA) = 1.0
        for (int t = 0; t < 256; ++t) {
            chunk_in[t] = carry;
            carry = chunk_p[t] * carry + chunk_e[t];
        }
    }
    __syncthreads();
    float prev = chunk_in[tid];
    float g = 0.f;
    for (int i = start; i < end; ++i) {
        float r2 = sc[i] * sc[i];
        float cv = OMEGA + ALPHA * r2 + BETA * prev;
        prev = cv;
        // -lp (without constant): 0.5*log(0.5*cv) + 2.5*log1p(r2/(2*cv))
        g += 0.5f * logf(0.5f * cv) + 2.5f * log1pf(r2 / (2.f * cv));
    }
    g = wave_sum(g);
    __syncthreads();
    if (lane == 0) s4[wv] = g;
    __syncthreads();
    if (tid == 0) g_shared = s4[0] + s4[1] + s4[2] + s4[3];

    // 5) recon partials in double
    double ds = 0.0;
    for (int i = tid; i < NBLK1; i += 256) ds += (double)partials[i];
    for (int o = 32; o > 0; o >>= 1) ds += __shfl_down(ds, o);
    if (lane == 0) d4[wv] = ds;
    __syncthreads();

    if (tid == 0) {
        const double LOG_2PI = 1.8378770664093453;
        // gammaln(2.5) - gammaln(2.0) - 0.5*log(4*pi) = -0.9808292530117262
        const double NEG_C = 0.9808292530117262;
        double q = d4[0] + d4[1] + d4[2] + d4[3];
        double recon = 0.5 * (q + N_TOTAL * LOG_2PI) / 4096.0;
        double acl   = (double)(aclw[0] + aclw[1] + aclw[2] + aclw[3]) / 50.0;
        double garch = (double)g_shared + (double)NS * NEG_C;
        out[0] = (float)(recon + 10.0 * acl + 0.001 * garch);
    }
}

extern "C" void kernel_launch(void* const* d_in, const int* in_sizes, int n_in,
                              void* d_out, int out_size, void* d_ws, size_t ws_size,
                              hipStream_t stream) {
    const float* x_true  = (const float*)d_in[0];   // 4096*512*8
    const float* dec_out = (const float*)d_in[1];   // 4096*512*16
    float* partials = (float*)d_ws;                 // NBLK1 floats
    float* out = (float*)d_out;

    recon_kernel<<<NBLK1, 256, 0, stream>>>(x_true, dec_out, partials);
    tail_kernel<<<1, 256, 0, stream>>>(dec_out, partials, out);
}

// Round 2
// 259.492 us; speedup vs baseline: 1.1355x; 1.1355x over previous
//
#include <hip/hip_runtime.h>

// ---------------- constants ----------------
#define NS        4607          // series length: 512 + 4095
#define NBLK1     8192          // recon blocks
#define PX_PER_BLK 256          // pixels (batch*time positions) per recon block
#define N_TOTAL   16777216.0    // 4096*512*8 elements in recon sum

// ws layout (floats):
//  [0, NBLK1)            recon partials
//  [NBLK1, NBLK1+NS)     centered series sc
//  NBLK1+NS              var
//  NBLK1+NS+1            garch sum
//  [NBLK1+NS+2, +50)     acl r^2 per lag
#define WS_SC    (NBLK1)
#define WS_VAR   (NBLK1 + NS)
#define WS_GARCH (NBLK1 + NS + 1)
#define WS_ACL   (NBLK1 + NS + 2)

__device__ __forceinline__ float wave_sum(float v) {
    for (int o = 32; o > 0; o >>= 1) v += __shfl_down(v, o);
    return v;
}

// -------- Kernel 1: recon partial sums, fully-contiguous global streams --------
// dec tile staged to LDS (pixel stride 20 words to break bank conflicts);
// x consumed directly as contiguous float4 per-lane streams.
__global__ __launch_bounds__(256) void recon_kernel(
    const float* __restrict__ x, const float* __restrict__ dec,
    float* __restrict__ partials)
{
    __shared__ float ldsDec[PX_PER_BLK * 20];   // 20 KB
    const int tid = threadIdx.x;
    const long long pixBase = (long long)blockIdx.x * PX_PER_BLK;

    // stage dec tile: 256 px * 16 floats = 1024 float4s, contiguous lane access
    const float4* dec4 = (const float4*)(dec + pixBase * 16);
#pragma unroll
    for (int s = 0; s < 4; ++s) {
        const int w   = tid + s * 256;      // [0,1024)
        const int pix = w >> 2, q = w & 3;  // quarter q: 0,1=mean halves; 2,3=logvar halves
        float4 v = dec4[w];
        *(float4*)(&ldsDec[pix * 20 + q * 4]) = v;
    }
    __syncthreads();

    const float4* x4 = (const float4*)(x + pixBase * 8);
    float acc = 0.f;
#pragma unroll
    for (int k = 0; k < 2; ++k) {
        const int u   = tid + k * 256;      // [0,512) x-float4 index
        const int pix = u >> 1, h = u & 1;
        float4 xv = x4[u];
        float4 m  = *(const float4*)(&ldsDec[pix * 20 + h * 4]);
        float4 lv = *(const float4*)(&ldsDec[pix * 20 + 8 + h * 4]);
        float d;
        d = xv.x - m.x; acc += lv.x + d * d * __expf(-lv.x);
        d = xv.y - m.y; acc += lv.y + d * d * __expf(-lv.y);
        d = xv.z - m.z; acc += lv.z + d * d * __expf(-lv.z);
        d = xv.w - m.w; acc += lv.w + d * d * __expf(-lv.w);
    }

    acc = wave_sum(acc);
    __shared__ float s4[4];
    if ((tid & 63) == 0) s4[tid >> 6] = acc;
    __syncthreads();
    if (tid == 0) partials[blockIdx.x] = s4[0] + s4[1] + s4[2] + s4[3];
}

// -------- Kernel 2a: series gather + mean/center/var + GARCH (1 block) --------
__global__ __launch_bounds__(256) void series_kernel(
    const float* __restrict__ dec, float* __restrict__ ws)
{
    const float OMEGA = 0.05f, ALPHA = 0.1f, BETA = 0.85f;
    const int tid  = threadIdx.x;
    const int lane = tid & 63;
    const int wv   = tid >> 6;

    __shared__ float sc[NS];
    __shared__ float s4[4];
    __shared__ float chunk_e[256], chunk_p[256], chunk_in[256];

    // gather series into LDS
    float lsum = 0.f;
    for (int j = tid; j < NS; j += 256) {
        float v = (j < 512) ? dec[(long long)j * 16]
                            : dec[(long long)(j - 511) * 8192 + 8176];
        sc[j] = v;
        lsum += v;
    }
    lsum = wave_sum(lsum);
    __syncthreads();
    if (lane == 0) s4[wv] = lsum;
    __syncthreads();
    const float mean = (s4[0] + s4[1] + s4[2] + s4[3]) / (float)NS;

    // center, variance, spill centered series to global for ACL blocks
    float vsum = 0.f;
    __syncthreads();
    for (int j = tid; j < NS; j += 256) {
        float v = sc[j] - mean;
        sc[j] = v;
        ws[WS_SC + j] = v;
        vsum += v * v;
    }
    vsum = wave_sum(vsum);
    __syncthreads();
    if (lane == 0) s4[wv] = vsum;
    __syncthreads();
    const float var = s4[0] + s4[1] + s4[2] + s4[3];

    // GARCH: chunked parallel linear-recurrence scan (L=18 per thread)
    const int start = tid * 18;
    const int end   = min(start + 18, NS);
    float e = 0.f, p = 1.f;
    for (int i = start; i < end; ++i) {
        float r2 = sc[i] * sc[i];
        e = (OMEGA + ALPHA * r2) + BETA * e;
        p *= BETA;
    }
    chunk_e[tid] = e; chunk_p[tid] = p;
    __syncthreads();
    if (tid == 0) {
        float carry = 1.0f;  // sigma0 = OMEGA/(1-ALPHA-BETA) = 1.0
        for (int t = 0; t < 256; ++t) {
            chunk_in[t] = carry;
            carry = chunk_p[t] * carry + chunk_e[t];
        }
    }
    __syncthreads();
    float prev = chunk_in[tid];
    float g = 0.f;
    for (int i = start; i < end; ++i) {
        float r2 = sc[i] * sc[i];
        float cv = OMEGA + ALPHA * r2 + BETA * prev;
        prev = cv;
        // -lp (without the per-sample constant):
        g += 0.5f * logf(0.5f * cv) + 2.5f * log1pf(r2 / (2.f * cv));
    }
    g = wave_sum(g);
    __syncthreads();
    if (lane == 0) s4[wv] = g;
    __syncthreads();
    if (tid == 0) {
        ws[WS_VAR]   = var;
        ws[WS_GARCH] = s4[0] + s4[1] + s4[2] + s4[3];
    }
}

// -------- Kernel 2b: ACL, one lag per block (50 blocks) --------
__global__ __launch_bounds__(256) void acl_kernel(float* __restrict__ ws)
{
    const int tid  = threadIdx.x;
    const int lane = tid & 63;
    const int wv   = tid >> 6;
    const int k    = blockIdx.x + 1;   // lag 1..50

    __shared__ float sc[NS];
    __shared__ float s4[4];
    for (int j = tid; j < NS; j += 256) sc[j] = ws[WS_SC + j];
    __syncthreads();

    float a = 0.f;
    for (int i = tid; i < NS - k; i += 256) a += sc[i] * sc[i + k];
    a = wave_sum(a);
    if (lane == 0) s4[wv] = a;
    __syncthreads();
    if (tid == 0) {
        float r = (s4[0] + s4[1] + s4[2] + s4[3]) / ws[WS_VAR];
        ws[WS_ACL + (k - 1)] = r * r;
    }
}

// -------- Kernel 3: final combine --------
__global__ __launch_bounds__(256) void final_kernel(
    const float* __restrict__ ws, float* __restrict__ out)
{
    const int tid  = threadIdx.x;
    const int lane = tid & 63;
    const int wv   = tid >> 6;
    __shared__ double d4[4];
    __shared__ float  aclbuf[64];

    // recon partials in double
    double ds = 0.0;
    for (int i = tid; i < NBLK1; i += 256) ds += (double)ws[i];
    for (int o = 32; o > 0; o >>= 1) ds += __shfl_down(ds, o);
    if (lane == 0) d4[wv] = ds;

    // acl parts (50 values) summed by wave 0
    if (wv == 0) {
        float av = (lane < 50) ? ws[WS_ACL + lane] : 0.f;
        av = wave_sum(av);
        if (lane == 0) aclbuf[0] = av;
    }
    __syncthreads();

    if (tid == 0) {
        const double LOG_2PI = 1.8378770664093453;
        // gammaln(2.5) - gammaln(2.0) - 0.5*log(4*pi) = -0.9808292530117262
        const double NEG_C = 0.9808292530117262;
        double q = d4[0] + d4[1] + d4[2] + d4[3];
        double recon = 0.5 * (q + N_TOTAL * LOG_2PI) / 4096.0;
        double acl   = (double)aclbuf[0] / 50.0;
        double garch = (double)ws[WS_GARCH] + (double)NS * NEG_C;
        out[0] = (float)(recon + 10.0 * acl + 0.001 * garch);
    }
}

extern "C" void kernel_launch(void* const* d_in, const int* in_sizes, int n_in,
                              void* d_out, int out_size, void* d_ws, size_t ws_size,
                              hipStream_t stream) {
    const float* x_true  = (const float*)d_in[0];   // 4096*512*8
    const float* dec_out = (const float*)d_in[1];   // 4096*512*16
    float* ws  = (float*)d_ws;
    float* out = (float*)d_out;

    recon_kernel<<<NBLK1, 256, 0, stream>>>(x_true, dec_out, ws);
    series_kernel<<<1, 256, 0, stream>>>(dec_out, ws);
    acl_kernel<<<50, 256, 0, stream>>>(ws);
    final_kernel<<<1, 256, 0, stream>>>(ws, out);
}

// Round 3
// 252.260 us; speedup vs baseline: 1.1681x; 1.0287x over previous
//
#include <hip/hip_runtime.h>

// ---------------- constants ----------------
#define NS        4607          // series length: 512 + 4095
#define NBLK1     8192          // recon blocks
#define N_TOTAL   16777216.0    // 4096*512*8 elements in recon sum

// ws layout (floats):
#define WS_PART  0              // [0, 8192)       recon partials
#define WS_SRAW  8192           // [8192, +NS)     raw series values
#define WS_GARCH (8192 + NS)    // garch sum
#define WS_ACL   (8192 + NS + 1)// 50 acl r^2 values

__device__ __forceinline__ float wave_sum(float v) {
    for (int o = 32; o > 0; o >>= 1) v += __shfl_down(v, o);
    return v;
}

// -------- Kernel 1: recon partial sums + series extraction --------
__global__ __launch_bounds__(256) void recon_kernel(
    const float* __restrict__ x, const float* __restrict__ dec,
    float* __restrict__ ws)
{
    __shared__ float ldsDec[256 * 20];   // 20 KB, pix stride 20 (bank-conflict-free)
    const int tid = threadIdx.x;
    const long long pixBase = (long long)blockIdx.x * 256;

    const float4* dec4 = (const float4*)(dec + pixBase * 16);
    const float4* x4   = (const float4*)(x + pixBase * 8);

    // issue ALL global loads up front (dec tile + x), fully lane-contiguous
    float4 d0 = dec4[tid], d1 = dec4[tid + 256],
           d2 = dec4[tid + 512], d3 = dec4[tid + 768];
    float4 xv0 = x4[tid], xv1 = x4[tid + 256];

    // stage dec to LDS: float4 w -> pix = w>>2, quarter q = w&3
    {
        int w, pix, q;
        w = tid;        pix = w >> 2; q = w & 3; *(float4*)(&ldsDec[pix*20 + q*4]) = d0;
        w = tid + 256;  pix = w >> 2; q = w & 3; *(float4*)(&ldsDec[pix*20 + q*4]) = d1;
        w = tid + 512;  pix = w >> 2; q = w & 3; *(float4*)(&ldsDec[pix*20 + q*4]) = d2;
        w = tid + 768;  pix = w >> 2; q = w & 3; *(float4*)(&ldsDec[pix*20 + q*4]) = d3;
    }
    __syncthreads();

    float acc = 0.f;
#pragma unroll
    for (int k = 0; k < 2; ++k) {
        const int u   = tid + k * 256;      // [0,512) task index
        const int pl  = u >> 1, h = u & 1;  // local pixel, half
        float4 xv = k ? xv1 : xv0;
        float4 m  = *(const float4*)(&ldsDec[pl * 20 + h * 4]);
        float4 lv = *(const float4*)(&ldsDec[pl * 20 + 8 + h * 4]);
        float d;
        d = xv.x - m.x; acc += lv.x + d * d * __expf(-lv.x);
        d = xv.y - m.y; acc += lv.y + d * d * __expf(-lv.y);
        d = xv.z - m.z; acc += lv.z + d * d * __expf(-lv.z);
        d = xv.w - m.w; acc += lv.w + d * d * __expf(-lv.w);

        // series extraction: element 0 of pixel = m.x when h==0
        if (h == 0) {
            const long long pix = pixBase + pl;
            if (pix < 512)                 ws[WS_SRAW + (int)pix] = m.x;
            else if ((pix & 511) == 511)   ws[WS_SRAW + (int)(pix >> 9) + 511] = m.x;
        }
    }

    acc = wave_sum(acc);
    __shared__ float s4[4];
    if ((tid & 63) == 0) s4[tid >> 6] = acc;
    __syncthreads();
    if (tid == 0) ws[WS_PART + blockIdx.x] = s4[0] + s4[1] + s4[2] + s4[3];
}

// -------- Kernel 2: tail (51 blocks): block 0 = GARCH, blocks 1..50 = ACL lag --------
__global__ __launch_bounds__(256) void tail_kernel(float* __restrict__ ws)
{
    const float OMEGA = 0.05f, ALPHA = 0.1f, BETA = 0.85f;
    const int tid  = threadIdx.x;
    const int lane = tid & 63;
    const int wv   = tid >> 6;

    __shared__ float sc[NS];
    __shared__ float s4[4];

    // load raw series (contiguous, L2-hot), block mean
    float lsum = 0.f;
    for (int j = tid; j < NS; j += 256) { float v = ws[WS_SRAW + j]; sc[j] = v; lsum += v; }
    lsum = wave_sum(lsum);
    __syncthreads();
    if (lane == 0) s4[wv] = lsum;
    __syncthreads();
    const float mean = (s4[0] + s4[1] + s4[2] + s4[3]) / (float)NS;

    // center in LDS + variance
    float vsum = 0.f;
    __syncthreads();
    for (int j = tid; j < NS; j += 256) { float v = sc[j] - mean; sc[j] = v; vsum += v * v; }
    vsum = wave_sum(vsum);
    __syncthreads();
    if (lane == 0) s4[wv] = vsum;
    __syncthreads();
    const float var = s4[0] + s4[1] + s4[2] + s4[3];

    if (blockIdx.x == 0) {
        // ---- GARCH: chunked scan, shfl-based compose (segment: x_out = p*x_in + e) ----
        const int start = tid * 18;
        const int end   = min(start + 18, NS);
        float e = 0.f, p = 1.f;
        for (int i = start; i < end; ++i) {
            float r2 = sc[i] * sc[i];
            e = (OMEGA + ALPHA * r2) + BETA * e;
            p *= BETA;
        }
        // wave-level inclusive scan (Hillis-Steele)
        for (int o = 1; o < 64; o <<= 1) {
            float pe = __shfl_up(e, o), pp = __shfl_up(p, o);
            if (lane >= o) { e = e + p * pe; p = p * pp; }
        }
        __shared__ float wE[4], wP[4];
        if (lane == 63) { wE[wv] = e; wP[wv] = p; }
        __syncthreads();
        // carry = compose of full waves 0..wv-1
        float cE = 0.f, cP = 1.f;
        for (int t = 0; t < wv; ++t) { cE = wE[t] + wP[t] * cE; cP = wP[t] * cP; }
        // exclusive within-wave prefix
        float eE = __shfl_up(e, 1), eP = __shfl_up(p, 1);
        if (lane == 0) { eE = 0.f; eP = 1.f; }
        // sigma0 = OMEGA/(1-ALPHA-BETA) = 1.0
        float prev = (eE + eP * cE) + (eP * cP) * 1.0f;
        float g = 0.f;
        for (int i = start; i < end; ++i) {
            float r2 = sc[i] * sc[i];
            float cv = OMEGA + ALPHA * r2 + BETA * prev;
            prev = cv;
            g += 0.5f * logf(0.5f * cv) + 2.5f * log1pf(r2 / (2.f * cv));
        }
        g = wave_sum(g);
        __syncthreads();
        if (lane == 0) s4[wv] = g;
        __syncthreads();
        if (tid == 0) ws[WS_GARCH] = s4[0] + s4[1] + s4[2] + s4[3];
    } else {
        // ---- ACL lag k ----
        const int k = blockIdx.x;   // 1..50
        float a = 0.f;
        for (int i = tid; i < NS - k; i += 256) a += sc[i] * sc[i + k];
        a = wave_sum(a);
        __syncthreads();
        if (lane == 0) s4[wv] = a;
        __syncthreads();
        if (tid == 0) {
            float r = (s4[0] + s4[1] + s4[2] + s4[3]) / var;
            ws[WS_ACL + (k - 1)] = r * r;
        }
    }
}

// -------- Kernel 3: final combine --------
__global__ __launch_bounds__(256) void final_kernel(
    const float* __restrict__ ws, float* __restrict__ out)
{
    const int tid  = threadIdx.x;
    const int lane = tid & 63;
    const int wv   = tid >> 6;
    __shared__ double d4[4];
    __shared__ float  aclbuf[1];

    double ds = 0.0;
    for (int i = tid; i < NBLK1; i += 256) ds += (double)ws[WS_PART + i];
    for (int o = 32; o > 0; o >>= 1) ds += __shfl_down(ds, o);
    if (lane == 0) d4[wv] = ds;

    if (wv == 0) {
        float av = (lane < 50) ? ws[WS_ACL + lane] : 0.f;
        av = wave_sum(av);
        if (lane == 0) aclbuf[0] = av;
    }
    __syncthreads();

    if (tid == 0) {
        const double LOG_2PI = 1.8378770664093453;
        // -(gammaln(2.5) - gammaln(2.0) - 0.5*log(4*pi)) = 0.9808292530117262
        const double NEG_C = 0.9808292530117262;
        double q = d4[0] + d4[1] + d4[2] + d4[3];
        double recon = 0.5 * (q + N_TOTAL * LOG_2PI) / 4096.0;
        double acl   = (double)aclbuf[0] / 50.0;
        double garch = (double)ws[WS_GARCH] + (double)NS * NEG_C;
        out[0] = (float)(recon + 10.0 * acl + 0.001 * garch);
    }
}

extern "C" void kernel_launch(void* const* d_in, const int* in_sizes, int n_in,
                              void* d_out, int out_size, void* d_ws, size_t ws_size,
                              hipStream_t stream) {
    const float* x_true  = (const float*)d_in[0];   // 4096*512*8
    const float* dec_out = (const float*)d_in[1];   // 4096*512*16
    float* ws  = (float*)d_ws;
    float* out = (float*)d_out;

    recon_kernel<<<NBLK1, 256, 0, stream>>>(x_true, dec_out, ws);
    tail_kernel<<<51, 256, 0, stream>>>(ws);
    final_kernel<<<1, 256, 0, stream>>>(ws, out);
}

// Round 4
// 251.409 us; speedup vs baseline: 1.1720x; 1.0034x over previous
//
#include <hip/hip_runtime.h>

// ---------------- constants ----------------
#define NS        4607          // series length: 512 + 4095
#define NBLK1     8192          // recon blocks
#define N_TOTAL   16777216.0    // 4096*512*8 elements in recon sum

// ws layout (floats):
#define WS_PART   0               // [0, 8192)    recon partials
#define WS_SRAW   8192            // [+NS)        raw series values
#define WS_GARCH  (8192 + NS)     // garch sum (atomic accum, zero-inited by recon)
#define WS_ACLSUM (8192 + NS + 1) // sum of acl r^2 (atomic accum, zero-inited)
#define WS_CNT    (8192 + NS + 2) // int arrival counter (zero-inited)

__device__ __forceinline__ float wave_sum(float v) {
    for (int o = 32; o > 0; o >>= 1) v += __shfl_down(v, o);
    return v;
}

// -------- Kernel 1: recon partial sums + series extraction (no LDS staging) --------
// dec layout per pixel: 16 floats = 4 float4 quarters [q0,q1]=mean, [q2,q3]=logvar.
// Thread w loads quarter q=w&3 of pixel w>>2; lanes w and w^2 swap via shfl_xor(2)
// so every lane holds a matching (mean,logvar) quarter pair. Each element is
// computed by exactly 2 lanes -> block partial scaled by 0.5 (exact).
__global__ __launch_bounds__(256) void recon_kernel(
    const float* __restrict__ x, const float* __restrict__ dec,
    float* __restrict__ ws)
{
    const int tid = threadIdx.x;
    const long long pixBase = (long long)blockIdx.x * 256;
    const float4* dec4 = (const float4*)(dec + pixBase * 16);
    const float4* x4   = (const float4*)(x + pixBase * 8);

    // issue all 8 global loads up front; dec fully lane-contiguous,
    // x: 2 lanes per address (coalescer merges), contiguous segments.
    float4 dv[4], xv[4];
#pragma unroll
    for (int r = 0; r < 4; ++r) {
        const int w = tid + r * 256;
        dv[r] = dec4[w];
        const int u = ((w >> 2) << 1) | (w & 1);   // pixel*2 + half
        xv[r] = x4[u];
    }

    float acc = 0.f;
#pragma unroll
    for (int r = 0; r < 4; ++r) {
        const int w = tid + r * 256;
        const int q = w & 3;
        float4 a = dv[r], b;
        b.x = __shfl_xor(a.x, 2);
        b.y = __shfl_xor(a.y, 2);
        b.z = __shfl_xor(a.z, 2);
        b.w = __shfl_xor(a.w, 2);
        const bool im = (q < 2);               // true: a=mean, b=logvar
        float4 m, lv;
        m.x  = im ? a.x : b.x;  m.y  = im ? a.y : b.y;
        m.z  = im ? a.z : b.z;  m.w  = im ? a.w : b.w;
        lv.x = im ? b.x : a.x;  lv.y = im ? b.y : a.y;
        lv.z = im ? b.z : a.z;  lv.w = im ? b.w : a.w;
        float4 xx = xv[r];
        float d;
        d = xx.x - m.x; acc += lv.x + d * d * __expf(-lv.x);
        d = xx.y - m.y; acc += lv.y + d * d * __expf(-lv.y);
        d = xx.z - m.z; acc += lv.z + d * d * __expf(-lv.z);
        d = xx.w - m.w; acc += lv.w + d * d * __expf(-lv.w);

        // series extraction: element 0 of pixel -> m.x on the q==0 lane
        if (q == 0) {
            const long long pix = pixBase + (w >> 2);
            if (pix < 512)               ws[WS_SRAW + (int)pix] = m.x;
            else if ((pix & 511) == 511) ws[WS_SRAW + (int)(pix >> 9) + 511] = m.x;
        }
    }

    acc = wave_sum(acc);
    __shared__ float s4[4];
    if ((tid & 63) == 0) s4[tid >> 6] = acc;
    __syncthreads();
    if (tid == 0) {
        ws[WS_PART + blockIdx.x] = 0.5f * (s4[0] + s4[1] + s4[2] + s4[3]);
        if (blockIdx.x == 0) {   // init accumulators for tail (visible at dispatch boundary)
            ws[WS_GARCH]  = 0.f;
            ws[WS_ACLSUM] = 0.f;
            ((int*)ws)[WS_CNT] = 0;
        }
    }
}

// -------- Kernel 2: tail (51 blocks): block 0 = GARCH, blocks 1..50 = ACL lag;
//          last-arriving block finalizes (sums recon partials, writes out). --------
__global__ __launch_bounds__(256) void tail_kernel(float* __restrict__ ws,
                                                   float* __restrict__ out)
{
    const float OMEGA = 0.05f, ALPHA = 0.1f, BETA = 0.85f;
    const int tid  = threadIdx.x;
    const int lane = tid & 63;
    const int wv   = tid >> 6;

    __shared__ float sc[NS];
    __shared__ float s4[4];
    __shared__ int   isLast;

    // load raw series (contiguous, L2-hot), block mean
    float lsum = 0.f;
    for (int j = tid; j < NS; j += 256) { float v = ws[WS_SRAW + j]; sc[j] = v; lsum += v; }
    lsum = wave_sum(lsum);
    __syncthreads();
    if (lane == 0) s4[wv] = lsum;
    __syncthreads();
    const float mean = (s4[0] + s4[1] + s4[2] + s4[3]) / (float)NS;

    // center in LDS + variance
    float vsum = 0.f;
    __syncthreads();
    for (int j = tid; j < NS; j += 256) { float v = sc[j] - mean; sc[j] = v; vsum += v * v; }
    vsum = wave_sum(vsum);
    __syncthreads();
    if (lane == 0) s4[wv] = vsum;
    __syncthreads();
    const float var = s4[0] + s4[1] + s4[2] + s4[3];

    if (blockIdx.x == 0) {
        // ---- GARCH: chunked scan, shfl compose (segment: x_out = p*x_in + e) ----
        const int start = tid * 18;
        const int end   = min(start + 18, NS);
        float e = 0.f, p = 1.f;
        for (int i = start; i < end; ++i) {
            float r2 = sc[i] * sc[i];
            e = (OMEGA + ALPHA * r2) + BETA * e;
            p *= BETA;
        }
        for (int o = 1; o < 64; o <<= 1) {          // wave inclusive scan
            float pe = __shfl_up(e, o), pp = __shfl_up(p, o);
            if (lane >= o) { e = e + p * pe; p = p * pp; }
        }
        __shared__ float wE[4], wP[4];
        if (lane == 63) { wE[wv] = e; wP[wv] = p; }
        __syncthreads();
        float cE = 0.f, cP = 1.f;
        for (int t = 0; t < wv; ++t) { cE = wE[t] + wP[t] * cE; cP = wP[t] * cP; }
        float eE = __shfl_up(e, 1), eP = __shfl_up(p, 1);
        if (lane == 0) { eE = 0.f; eP = 1.f; }
        float prev = (eE + eP * cE) + (eP * cP) * 1.0f;   // sigma0 = 1.0
        float g = 0.f;
        for (int i = start; i < end; ++i) {
            float r2 = sc[i] * sc[i];
            float cv = OMEGA + ALPHA * r2 + BETA * prev;
            prev = cv;
            g += 0.5f * logf(0.5f * cv) + 2.5f * log1pf(r2 / (2.f * cv));
        }
        g = wave_sum(g);
        __syncthreads();
        if (lane == 0) s4[wv] = g;
        __syncthreads();
        if (tid == 0) atomicAdd(&ws[WS_GARCH], s4[0] + s4[1] + s4[2] + s4[3]);
    } else {
        // ---- ACL lag k ----
        const int k = blockIdx.x;   // 1..50
        float a = 0.f;
        for (int i = tid; i < NS - k; i += 256) a += sc[i] * sc[i + k];
        a = wave_sum(a);
        __syncthreads();
        if (lane == 0) s4[wv] = a;
        __syncthreads();
        if (tid == 0) {
            float r = (s4[0] + s4[1] + s4[2] + s4[3]) / var;
            atomicAdd(&ws[WS_ACLSUM], r * r);
        }
    }

    // ---- arrival ticket; last block finalizes ----
    __syncthreads();
    if (tid == 0) {
        __threadfence();
        isLast = (atomicAdd((int*)ws + WS_CNT, 1) == 50) ? 1 : 0;
    }
    __syncthreads();
    if (isLast) {
        __threadfence();
        __shared__ double d4[4];
        double ds = 0.0;   // recon partials (written by previous dispatch — coherent)
        for (int i = tid; i < NBLK1; i += 256) ds += (double)ws[WS_PART + i];
        for (int o = 32; o > 0; o >>= 1) ds += __shfl_down(ds, o);
        if (lane == 0) d4[wv] = ds;
        __syncthreads();
        if (tid == 0) {
            // atomic reads hit the coherent point (device scope)
            float garch_f = atomicAdd(&ws[WS_GARCH], 0.f);
            float acl_f   = atomicAdd(&ws[WS_ACLSUM], 0.f);
            const double LOG_2PI = 1.8378770664093453;
            const double NEG_C   = 0.9808292530117262; // -(gammaln(2.5)-gammaln(2)-0.5*log(4*pi))
            double q = d4[0] + d4[1] + d4[2] + d4[3];
            double recon = 0.5 * (q + N_TOTAL * LOG_2PI) / 4096.0;
            double acl   = (double)acl_f / 50.0;
            double garch = (double)garch_f + (double)NS * NEG_C;
            out[0] = (float)(recon + 10.0 * acl + 0.001 * garch);
        }
    }
}

extern "C" void kernel_launch(void* const* d_in, const int* in_sizes, int n_in,
                              void* d_out, int out_size, void* d_ws, size_t ws_size,
                              hipStream_t stream) {
    const float* x_true  = (const float*)d_in[0];   // 4096*512*8
    const float* dec_out = (const float*)d_in[1];   // 4096*512*16
    float* ws  = (float*)d_ws;
    float* out = (float*)d_out;

    recon_kernel<<<NBLK1, 256, 0, stream>>>(x_true, dec_out, ws);
    tail_kernel<<<51, 256, 0, stream>>>(ws, out);
}

// Round 6
// 246.074 us; speedup vs baseline: 1.1975x; 1.0217x over previous
//
#include <hip/hip_runtime.h>

// ---------------- constants ----------------
#define NS        4607          // series length: 512 + 4095
#define NRECON    8192          // recon tiles (256 pixels each)
#define NTAIL     51            // tail blocks: 0 = GARCH, 1..50 = ACL lag k
#define N_TOTAL   16777216.0    // 4096*512*8 elements in recon sum

// ws layout (floats):
#define WS_PART   0             // [0, 8192)  recon partials (slot = tile)
#define WS_GARCH  8192          // garch sum
#define WS_ACL    8193          // 50 acl r^2 values

__device__ __forceinline__ float wave_sum(float v) {
    for (int o = 32; o > 0; o >>= 1) v += __shfl_down(v, o);
    return v;
}

// -------- Kernel 1: recon blocks (51..8242) + tail blocks (0..50) concurrently --------
__global__ __launch_bounds__(256) void main_kernel(
    const float* __restrict__ x, const float* __restrict__ dec,
    float* __restrict__ ws)
{
    const int tid  = threadIdx.x;
    const int lane = tid & 63;
    const int wv   = tid >> 6;

    if (blockIdx.x >= NTAIL) {
        // ================= recon tile =================
        // dec per pixel: 4 float4 quarters [q0,q1]=mean, [q2,q3]=logvar.
        // Lanes w and w^2 swap quarters via shfl_xor(2); every element computed
        // by exactly 2 lanes -> block partial scaled by 0.5 (exact).
        const int tile = blockIdx.x - NTAIL;
        const long long pixBase = (long long)tile * 256;
        const float4* dec4 = (const float4*)(dec + pixBase * 16);
        const float4* x4   = (const float4*)(x + pixBase * 8);

        float4 dv[4], xv[4];
#pragma unroll
        for (int r = 0; r < 4; ++r) {
            const int w = tid + r * 256;
            dv[r] = dec4[w];
            const int u = ((w >> 2) << 1) | (w & 1);   // pixel*2 + half
            xv[r] = x4[u];
        }

        float acc = 0.f;
#pragma unroll
        for (int r = 0; r < 4; ++r) {
            const int w = tid + r * 256;
            const int q = w & 3;
            float4 a = dv[r], b;
            b.x = __shfl_xor(a.x, 2);
            b.y = __shfl_xor(a.y, 2);
            b.z = __shfl_xor(a.z, 2);
            b.w = __shfl_xor(a.w, 2);
            const bool im = (q < 2);               // a=mean half, b=logvar half
            float4 m, lv;
            m.x  = im ? a.x : b.x;  m.y  = im ? a.y : b.y;
            m.z  = im ? a.z : b.z;  m.w  = im ? a.w : b.w;
            lv.x = im ? b.x : a.x;  lv.y = im ? b.y : a.y;
            lv.z = im ? b.z : a.z;  lv.w = im ? b.w : a.w;
            float4 xx = xv[r];
            float d;
            d = xx.x - m.x; acc += lv.x + d * d * __expf(-lv.x);
            d = xx.y - m.y; acc += lv.y + d * d * __expf(-lv.y);
            d = xx.z - m.z; acc += lv.z + d * d * __expf(-lv.z);
            d = xx.w - m.w; acc += lv.w + d * d * __expf(-lv.w);
        }

        acc = wave_sum(acc);
        __shared__ float p4[4];
        if (lane == 0) p4[wv] = acc;
        __syncthreads();
        if (tid == 0) ws[WS_PART + tile] = 0.5f * (p4[0] + p4[1] + p4[2] + p4[3]);
    } else {
        // ================= tail block: gather series directly from dec =================
        const float OMEGA = 0.05f, ALPHA = 0.1f, BETA = 0.85f;
        __shared__ float sc[NS];
        __shared__ float s4[4];

        float lsum = 0.f;
        for (int j = tid; j < NS; j += 256) {
            float v = (j < 512) ? dec[(long long)j * 16]
                                : dec[(long long)(j - 511) * 8192 + 8176];
            sc[j] = v;
            lsum += v;
        }
        lsum = wave_sum(lsum);
        __syncthreads();
        if (lane == 0) s4[wv] = lsum;
        __syncthreads();
        const float mean = (s4[0] + s4[1] + s4[2] + s4[3]) / (float)NS;

        float vsum = 0.f;
        __syncthreads();
        for (int j = tid; j < NS; j += 256) { float v = sc[j] - mean; sc[j] = v; vsum += v * v; }
        vsum = wave_sum(vsum);
        __syncthreads();
        if (lane == 0) s4[wv] = vsum;
        __syncthreads();
        const float var = s4[0] + s4[1] + s4[2] + s4[3];

        if (blockIdx.x == 0) {
            // ---- GARCH: chunked scan, shfl compose (segment: x_out = p*x_in + e) ----
            const int start = tid * 18;
            const int end   = min(start + 18, NS);
            float e = 0.f, p = 1.f;
            for (int i = start; i < end; ++i) {
                float r2 = sc[i] * sc[i];
                e = (OMEGA + ALPHA * r2) + BETA * e;
                p *= BETA;
            }
            for (int o = 1; o < 64; o <<= 1) {          // wave inclusive scan
                float pe = __shfl_up(e, o), pp = __shfl_up(p, o);
                if (lane >= o) { e = e + p * pe; p = p * pp; }
            }
            __shared__ float wE[4], wP[4];
            if (lane == 63) { wE[wv] = e; wP[wv] = p; }
            __syncthreads();
            float cE = 0.f, cP = 1.f;
            for (int t = 0; t < wv; ++t) { cE = wE[t] + wP[t] * cE; cP = wP[t] * cP; }
            float eE = __shfl_up(e, 1), eP = __shfl_up(p, 1);
            if (lane == 0) { eE = 0.f; eP = 1.f; }
            float prev = (eE + eP * cE) + (eP * cP) * 1.0f;   // sigma0 = 1.0
            float g = 0.f;
            for (int i = start; i < end; ++i) {
                float r2 = sc[i] * sc[i];
                float cv = OMEGA + ALPHA * r2 + BETA * prev;
                prev = cv;
                g += 0.5f * logf(0.5f * cv) + 2.5f * log1pf(r2 / (2.f * cv));
            }
            g = wave_sum(g);
            __syncthreads();
            if (lane == 0) s4[wv] = g;
            __syncthreads();
            if (tid == 0) ws[WS_GARCH] = s4[0] + s4[1] + s4[2] + s4[3];
        } else {
            // ---- ACL lag k ----
            const int k = blockIdx.x;   // 1..50
            float a = 0.f;
            for (int i = tid; i < NS - k; i += 256) a += sc[i] * sc[i + k];
            a = wave_sum(a);
            __syncthreads();
            if (lane == 0) s4[wv] = a;
            __syncthreads();
            if (tid == 0) {
                float r = (s4[0] + s4[1] + s4[2] + s4[3]) / var;
                ws[WS_ACL + (k - 1)] = r * r;
            }
        }
    }
}

// -------- Kernel 2: final combine (dispatch boundary provides coherence) --------
__global__ __launch_bounds__(256) void final_kernel(
    const float* __restrict__ ws, float* __restrict__ out)
{
    const int tid  = threadIdx.x;
    const int lane = tid & 63;
    const int wv   = tid >> 6;
    __shared__ double d4[4];
    __shared__ float  aclbuf[1];

    double ds = 0.0;
    for (int i = tid; i < NRECON; i += 256) ds += (double)ws[WS_PART + i];
    for (int o = 32; o > 0; o >>= 1) ds += __shfl_down(ds, o);
    if (lane == 0) d4[wv] = ds;

    if (wv == 0) {
        float av = (lane < 50) ? ws[WS_ACL + lane] : 0.f;
        av = wave_sum(av);
        if (lane == 0) aclbuf[0] = av;
    }
    __syncthreads();

    if (tid == 0) {
        const double LOG_2PI = 1.8378770664093453;
        const double NEG_C   = 0.9808292530117262; // -(gammaln(2.5)-gammaln(2)-0.5*log(4*pi))
        double q = d4[0] + d4[1] + d4[2] + d4[3];
        double recon = 0.5 * (q + N_TOTAL * LOG_2PI) / 4096.0;
        double acl   = (double)aclbuf[0] / 50.0;
        double garch = (double)ws[WS_GARCH] + (double)NS * NEG_C;
        out[0] = (float)(recon + 10.0 * acl + 0.001 * garch);
    }
}

extern "C" void kernel_launch(void* const* d_in, const int* in_sizes, int n_in,
                              void* d_out, int out_size, void* d_ws, size_t ws_size,
                              hipStream_t stream) {
    const float* x_true  = (const float*)d_in[0];   // 4096*512*8
    const float* dec_out = (const float*)d_in[1];   // 4096*512*16
    float* ws  = (float*)d_ws;
    float* out = (float*)d_out;

    main_kernel<<<NRECON + NTAIL, 256, 0, stream>>>(x_true, dec_out, ws);
    final_kernel<<<1, 256, 0, stream>>>(ws, out);
}

// Round 7
// 242.111 us; speedup vs baseline: 1.2171x; 1.0164x over previous
//
#include <hip/hip_runtime.h>

// ---------------- constants ----------------
#define NS        4607          // series length: 512 + 4095
#define NTAIL     51            // tail blocks: 0 = GARCH, 1..50 = ACL lag k
#define RBLK      2048          // persistent recon blocks
#define TPB       4             // tiles (256 px) per recon block
#define N_TOTAL   16777216.0    // 4096*512*8 elements in recon sum

// ws layout (floats):
#define WS_PART   0             // [0, RBLK)  recon partials
#define WS_GARCH  RBLK          // garch sum
#define WS_ACL    (RBLK + 1)    // 50 acl r^2 values

__device__ __forceinline__ float wave_sum(float v) {
    for (int o = 32; o > 0; o >>= 1) v += __shfl_down(v, o);
    return v;
}

// -------- Kernel 1: persistent recon blocks + concurrent tail blocks --------
__global__ __launch_bounds__(256) void main_kernel(
    const float* __restrict__ x, const float* __restrict__ dec,
    float* __restrict__ ws)
{
    const int tid  = threadIdx.x;
    const int lane = tid & 63;
    const int wv   = tid >> 6;

    if (blockIdx.x >= NTAIL) {
        // ============ persistent recon: 4 tiles, A/B register double-buffer ============
        // dec per pixel: 4 float4 quarters [q0,q1]=mean, [q2,q3]=logvar.
        // Lane pair (w, w^2) swaps quarters via shfl_xor(2); q<2 lane computes
        // components {x,y} of its half-pixel, q>=2 lane computes {z,w} -> each
        // element computed exactly once.
        const int rb = blockIdx.x - NTAIL;
        float acc = 0.f;

        float4 dA[4], xA[4], dB[4], xB[4];

#define LOAD_TILE(T, DV, XV)                                                   \
        {                                                                      \
            const long long pixBase = ((long long)(rb * TPB + (T))) * 256;     \
            const float4* dec4 = (const float4*)(dec + pixBase * 16);          \
            const float4* x4   = (const float4*)(x + pixBase * 8);             \
            _Pragma("unroll")                                                  \
            for (int r = 0; r < 4; ++r) {                                      \
                const int w = tid + r * 256;                                   \
                DV[r] = dec4[w];                                               \
                XV[r] = x4[((w >> 2) << 1) | (w & 1)];                         \
            }                                                                  \
        }

#define COMP_TILE(DV, XV)                                                      \
        {                                                                      \
            _Pragma("unroll")                                                  \
            for (int r = 0; r < 4; ++r) {                                      \
                const int w = tid + r * 256;                                   \
                const int q = w & 3;                                           \
                float4 a = DV[r], b;                                           \
                b.x = __shfl_xor(a.x, 2);                                      \
                b.y = __shfl_xor(a.y, 2);                                      \
                b.z = __shfl_xor(a.z, 2);                                      \
                b.w = __shfl_xor(a.w, 2);                                      \
                const bool im = (q < 2);                                       \
                float4 xx = XV[r];                                             \
                float xe0 = im ? xx.x : xx.z;                                  \
                float me0 = im ? a.x  : b.z;                                   \
                float le0 = im ? b.x  : a.z;                                   \
                float xe1 = im ? xx.y : xx.w;                                  \
                float me1 = im ? a.y  : b.w;                                   \
                float le1 = im ? b.y  : a.w;                                   \
                float d0 = xe0 - me0;                                          \
                float d1 = xe1 - me1;                                          \
                acc += le0 + d0 * d0 * __expf(-le0);                           \
                acc += le1 + d1 * d1 * __expf(-le1);                           \
            }                                                                  \
        }

        LOAD_TILE(0, dA, xA);
        LOAD_TILE(1, dB, xB);
        COMP_TILE(dA, xA);
        LOAD_TILE(2, dA, xA);
        COMP_TILE(dB, xB);
        LOAD_TILE(3, dB, xB);
        COMP_TILE(dA, xA);
        COMP_TILE(dB, xB);

#undef LOAD_TILE
#undef COMP_TILE

        acc = wave_sum(acc);
        __shared__ float p4[4];
        if (lane == 0) p4[wv] = acc;
        __syncthreads();
        if (tid == 0) ws[WS_PART + rb] = p4[0] + p4[1] + p4[2] + p4[3];
    } else {
        // ================= tail block: gather series directly from dec =================
        const float OMEGA = 0.05f, ALPHA = 0.1f, BETA = 0.85f;
        __shared__ float sc[NS];
        __shared__ float s4[4];

        float lsum = 0.f;
        for (int j = tid; j < NS; j += 256) {
            float v = (j < 512) ? dec[(long long)j * 16]
                                : dec[(long long)(j - 511) * 8192 + 8176];
            sc[j] = v;
            lsum += v;
        }
        lsum = wave_sum(lsum);
        __syncthreads();
        if (lane == 0) s4[wv] = lsum;
        __syncthreads();
        const float mean = (s4[0] + s4[1] + s4[2] + s4[3]) / (float)NS;

        float vsum = 0.f;
        __syncthreads();
        for (int j = tid; j < NS; j += 256) { float v = sc[j] - mean; sc[j] = v; vsum += v * v; }
        vsum = wave_sum(vsum);
        __syncthreads();
        if (lane == 0) s4[wv] = vsum;
        __syncthreads();
        const float var = s4[0] + s4[1] + s4[2] + s4[3];

        if (blockIdx.x == 0) {
            // ---- GARCH: chunked scan, shfl compose (segment: x_out = p*x_in + e) ----
            const int start = tid * 18;
            const int end   = min(start + 18, NS);
            float e = 0.f, p = 1.f;
            for (int i = start; i < end; ++i) {
                float r2 = sc[i] * sc[i];
                e = (OMEGA + ALPHA * r2) + BETA * e;
                p *= BETA;
            }
            for (int o = 1; o < 64; o <<= 1) {          // wave inclusive scan
                float pe = __shfl_up(e, o), pp = __shfl_up(p, o);
                if (lane >= o) { e = e + p * pe; p = p * pp; }
            }
            __shared__ float wE[4], wP[4];
            if (lane == 63) { wE[wv] = e; wP[wv] = p; }
            __syncthreads();
            float cE = 0.f, cP = 1.f;
            for (int t = 0; t < wv; ++t) { cE = wE[t] + wP[t] * cE; cP = wP[t] * cP; }
            float eE = __shfl_up(e, 1), eP = __shfl_up(p, 1);
            if (lane == 0) { eE = 0.f; eP = 1.f; }
            float prev = (eE + eP * cE) + (eP * cP) * 1.0f;   // sigma0 = 1.0
            float g = 0.f;
            for (int i = start; i < end; ++i) {
                float r2 = sc[i] * sc[i];
                float cv = OMEGA + ALPHA * r2 + BETA * prev;
                prev = cv;
                g += 0.5f * logf(0.5f * cv) + 2.5f * log1pf(r2 / (2.f * cv));
            }
            g = wave_sum(g);
            __syncthreads();
            if (lane == 0) s4[wv] = g;
            __syncthreads();
            if (tid == 0) ws[WS_GARCH] = s4[0] + s4[1] + s4[2] + s4[3];
        } else {
            // ---- ACL lag k ----
            const int k = blockIdx.x;   // 1..50
            float a = 0.f;
            for (int i = tid; i < NS - k; i += 256) a += sc[i] * sc[i + k];
            a = wave_sum(a);
            __syncthreads();
            if (lane == 0) s4[wv] = a;
            __syncthreads();
            if (tid == 0) {
                float r = (s4[0] + s4[1] + s4[2] + s4[3]) / var;
                ws[WS_ACL + (k - 1)] = r * r;
            }
        }
    }
}

// -------- Kernel 2: final combine (dispatch boundary provides coherence) --------
__global__ __launch_bounds__(256) void final_kernel(
    const float* __restrict__ ws, float* __restrict__ out)
{
    const int tid  = threadIdx.x;
    const int lane = tid & 63;
    const int wv   = tid >> 6;
    __shared__ double d4[4];
    __shared__ float  aclbuf[1];

    double ds = 0.0;
    for (int i = tid; i < RBLK; i += 256) ds += (double)ws[WS_PART + i];
    for (int o = 32; o > 0; o >>= 1) ds += __shfl_down(ds, o);
    if (lane == 0) d4[wv] = ds;

    if (wv == 0) {
        float av = (lane < 50) ? ws[WS_ACL + lane] : 0.f;
        av = wave_sum(av);
        if (lane == 0) aclbuf[0] = av;
    }
    __syncthreads();

    if (tid == 0) {
        const double LOG_2PI = 1.8378770664093453;
        const double NEG_C   = 0.9808292530117262; // -(gammaln(2.5)-gammaln(2)-0.5*log(4*pi))
        double q = d4[0] + d4[1] + d4[2] + d4[3];
        double recon = 0.5 * (q + N_TOTAL * LOG_2PI) / 4096.0;
        double acl   = (double)aclbuf[0] / 50.0;
        double garch = (double)ws[WS_GARCH] + (double)NS * NEG_C;
        out[0] = (float)(recon + 10.0 * acl + 0.001 * garch);
    }
}

extern "C" void kernel_launch(void* const* d_in, const int* in_sizes, int n_in,
                              void* d_out, int out_size, void* d_ws, size_t ws_size,
                              hipStream_t stream) {
    const float* x_true  = (const float*)d_in[0];   // 4096*512*8
    const float* dec_out = (const float*)d_in[1];   // 4096*512*16
    float* ws  = (float*)d_ws;
    float* out = (float*)d_out;

    main_kernel<<<RBLK + NTAIL, 256, 0, stream>>>(x_true, dec_out, ws);
    final_kernel<<<1, 256, 0, stream>>>(ws, out);
}

// Round 8
// 229.918 us; speedup vs baseline: 1.2816x; 1.0530x over previous
//
#include <hip/hip_runtime.h>

// ---------------- constants ----------------
#define NS        4607          // series length: 512 + 4095
#define NTAIL     51            // tail blocks: 0 = GARCH, 1..50 = ACL lag k
#define RBLK      2048          // recon blocks
#define TPB       4             // tiles (256 px) per recon block
#define N_TOTAL   16777216.0    // 4096*512*8 elements in recon sum

// ws layout (floats):
#define WS_PART   0                     // [0, RBLK)  recon partials
#define WS_GARCH  RBLK                  // garch sum
#define WS_ACL    (RBLK + 1)            // 50 acl r^2 values
#define WS_SCR    (RBLK + 64)           // 51 private series buffers, stride 4672
#define SCR_STRIDE 4672

typedef float vf4 __attribute__((ext_vector_type(4)));

__device__ __forceinline__ float wave_sum(float v) {
    for (int o = 32; o > 0; o >>= 1) v += __shfl_down(v, o);
    return v;
}

// -------- Kernel 1: recon blocks (51..2098) + concurrent tail blocks (0..50) --------
__global__ __launch_bounds__(256) void main_kernel(
    const float* __restrict__ x, const float* __restrict__ dec,
    float* __restrict__ ws)
{
    const int tid  = threadIdx.x;
    const int lane = tid & 63;
    const int wv   = tid >> 6;
    __shared__ float s4[4];

    if (blockIdx.x >= NTAIL) {
        // ================= recon: 4 tiles; per tile force an 8-load burst =================
        // dec per pixel: 4 float4 quarters [q0,q1]=mean, [q2,q3]=logvar.
        // Lane pair (w, w^2) swaps quarters via shfl_xor(2); q<2 lane computes
        // components {x,y}, q>=2 lane {z,w} -> each element computed exactly once.
        const int rb = blockIdx.x - NTAIL;
        float acc = 0.f;

        for (int t = 0; t < TPB; ++t) {
            const long long pixBase = ((long long)(rb * TPB + t)) * 256;
            const vf4* dp = (const vf4*)(dec + pixBase * 16);
            const vf4* xp = (const vf4*)(x + pixBase * 8);

            vf4 dv[4], xv[4];
#pragma unroll
            for (int r = 0; r < 4; ++r) {
                const int w = tid + r * 256;
                dv[r] = __builtin_nontemporal_load(dp + w);
                xv[r] = __builtin_nontemporal_load(xp + (((w >> 2) << 1) | (w & 1)));
            }
            // scheduling fence: forbid sinking the loads into the compute below,
            // so all 8 loads stay in flight together (true per-wave MLP burst).
            asm volatile("" ::: "memory");

#pragma unroll
            for (int r = 0; r < 4; ++r) {
                const int w = tid + r * 256;
                const int q = w & 3;
                vf4 a = dv[r], b;
                b.x = __shfl_xor(a.x, 2);
                b.y = __shfl_xor(a.y, 2);
                b.z = __shfl_xor(a.z, 2);
                b.w = __shfl_xor(a.w, 2);
                const bool im = (q < 2);
                vf4 xx = xv[r];
                float xe0 = im ? xx.x : xx.z;
                float me0 = im ? a.x  : b.z;
                float le0 = im ? b.x  : a.z;
                float xe1 = im ? xx.y : xx.w;
                float me1 = im ? a.y  : b.w;
                float le1 = im ? b.y  : a.w;
                float d0 = xe0 - me0;
                float d1 = xe1 - me1;
                acc += le0 + d0 * d0 * __expf(-le0);
                acc += le1 + d1 * d1 * __expf(-le1);
            }
        }

        acc = wave_sum(acc);
        if (lane == 0) s4[wv] = acc;
        __syncthreads();
        if (tid == 0) ws[WS_PART + rb] = s4[0] + s4[1] + s4[2] + s4[3];
    } else {
        // ============ tail block: private global scratch (no big LDS) ============
        const float OMEGA = 0.05f, ALPHA = 0.1f, BETA = 0.85f;
        float* scr = ws + WS_SCR + blockIdx.x * SCR_STRIDE;

        // gather series from dec (strided; hidden under recon), raw -> scratch
        float lsum = 0.f;
        for (int j = tid; j < NS; j += 256) {
            float v = (j < 512) ? dec[(long long)j * 16]
                                : dec[(long long)(j - 511) * 8192 + 8176];
            scr[j] = v;
            lsum += v;
        }
        lsum = wave_sum(lsum);
        __syncthreads();
        if (lane == 0) s4[wv] = lsum;
        __syncthreads();
        const float mean = (s4[0] + s4[1] + s4[2] + s4[3]) / (float)NS;

        // center in scratch + variance
        float vsum = 0.f;
        __syncthreads();
        for (int j = tid; j < NS; j += 256) {
            float v = scr[j] - mean;
            scr[j] = v;
            vsum += v * v;
        }
        vsum = wave_sum(vsum);
        __syncthreads();
        if (lane == 0) s4[wv] = vsum;
        __syncthreads();
        const float var = s4[0] + s4[1] + s4[2] + s4[3];

        if (blockIdx.x == 0) {
            // ---- GARCH: chunked scan, shfl compose (segment: x_out = p*x_in + e) ----
            const int start = tid * 18;
            const int end   = min(start + 18, NS);
            float e = 0.f, p = 1.f;
            for (int i = start; i < end; ++i) {
                float r2 = scr[i] * scr[i];
                e = (OMEGA + ALPHA * r2) + BETA * e;
                p *= BETA;
            }
            for (int o = 1; o < 64; o <<= 1) {          // wave inclusive scan
                float pe = __shfl_up(e, o), pp = __shfl_up(p, o);
                if (lane >= o) { e = e + p * pe; p = p * pp; }
            }
            __shared__ float wE[4], wP[4];
            if (lane == 63) { wE[wv] = e; wP[wv] = p; }
            __syncthreads();
            float cE = 0.f, cP = 1.f;
            for (int t = 0; t < wv; ++t) { cE = wE[t] + wP[t] * cE; cP = wP[t] * cP; }
            float eE = __shfl_up(e, 1), eP = __shfl_up(p, 1);
            if (lane == 0) { eE = 0.f; eP = 1.f; }
            float prev = (eE + eP * cE) + (eP * cP) * 1.0f;   // sigma0 = 1.0
            float g = 0.f;
            for (int i = start; i < end; ++i) {
                float r2 = scr[i] * scr[i];
                float cv = OMEGA + ALPHA * r2 + BETA * prev;
                prev = cv;
                g += 0.5f * logf(0.5f * cv) + 2.5f * log1pf(r2 / (2.f * cv));
            }
            g = wave_sum(g);
            __syncthreads();
            if (lane == 0) s4[wv] = g;
            __syncthreads();
            if (tid == 0) ws[WS_GARCH] = s4[0] + s4[1] + s4[2] + s4[3];
        } else {
            // ---- ACL lag k ----
            const int k = blockIdx.x;   // 1..50
            float a = 0.f;
            for (int i = tid; i < NS - k; i += 256) a += scr[i] * scr[i + k];
            a = wave_sum(a);
            __syncthreads();
            if (lane == 0) s4[wv] = a;
            __syncthreads();
            if (tid == 0) {
                float r = (s4[0] + s4[1] + s4[2] + s4[3]) / var;
                ws[WS_ACL + (k - 1)] = r * r;
            }
        }
    }
}

// -------- Kernel 2: final combine (dispatch boundary provides coherence) --------
__global__ __launch_bounds__(256) void final_kernel(
    const float* __restrict__ ws, float* __restrict__ out)
{
    const int tid  = threadIdx.x;
    const int lane = tid & 63;
    const int wv   = tid >> 6;
    __shared__ double d4[4];
    __shared__ float  aclbuf[1];

    double ds = 0.0;
    for (int i = tid; i < RBLK; i += 256) ds += (double)ws[WS_PART + i];
    for (int o = 32; o > 0; o >>= 1) ds += __shfl_down(ds, o);
    if (lane == 0) d4[wv] = ds;

    if (wv == 0) {
        float av = (lane < 50) ? ws[WS_ACL + lane] : 0.f;
        av = wave_sum(av);
        if (lane == 0) aclbuf[0] = av;
    }
    __syncthreads();

    if (tid == 0) {
        const double LOG_2PI = 1.8378770664093453;
        const double NEG_C   = 0.9808292530117262; // -(gammaln(2.5)-gammaln(2)-0.5*log(4*pi))
        double q = d4[0] + d4[1] + d4[2] + d4[3];
        double recon = 0.5 * (q + N_TOTAL * LOG_2PI) / 4096.0;
        double acl   = (double)aclbuf[0] / 50.0;
        double garch = (double)ws[WS_GARCH] + (double)NS * NEG_C;
        out[0] = (float)(recon + 10.0 * acl + 0.001 * garch);
    }
}

extern "C" void kernel_launch(void* const* d_in, const int* in_sizes, int n_in,
                              void* d_out, int out_size, void* d_ws, size_t ws_size,
                              hipStream_t stream) {
    const float* x_true  = (const float*)d_in[0];   // 4096*512*8
    const float* dec_out = (const float*)d_in[1];   // 4096*512*16
    float* ws  = (float*)d_ws;
    float* out = (float*)d_out;

    main_kernel<<<RBLK + NTAIL, 256, 0, stream>>>(x_true, dec_out, ws);
    final_kernel<<<1, 256, 0, stream>>>(ws, out);
}